// Round 10
// baseline (561.324 us; speedup 1.0000x reference)
//
#include <hip/hip_runtime.h>

#define N_NODES 50000
#define N_ENT   100000
#define N_REL   16
#define DIM     128
#define E_EDGES 600000
#define NQ      8192
#define PATH_DIM 5
#define NK      (N_NODES * N_REL)        /* 800000 (rel,dst) segments, rel-major */
#define NBLK_SEG (NK / 256)              /* 3125 */
#define KTOT    (N_REL * DIM + DIM)      /* 2176 */
#define NG      (KTOT / 32)              /* 68 */
#define BM      64                       /* rows per block */
#define EMAX    13                       /* static staged edges per wave-rel */
#define EB      ((E_EDGES + 255) / 256)
#define H0B     ((N_NODES * 32) / 256)
#define WCB     ((2 * NG * 8 * 512) / 256)

typedef __attribute__((ext_vector_type(8))) short short8;
typedef __attribute__((ext_vector_type(4))) float floatx4;

static __device__ __forceinline__ short f2bf(float x) {
  unsigned u = __builtin_bit_cast(unsigned, x);
  u = (u + 0x7FFFu + ((u >> 16) & 1u)) >> 16;   // RNE
  return (short)u;
}
static __device__ __forceinline__ float bf_lo(unsigned u) {
  return __builtin_bit_cast(float, u << 16);
}
static __device__ __forceinline__ float bf_hi(unsigned u) {
  return __builtin_bit_cast(float, u & 0xffff0000u);
}
static __device__ __forceinline__ unsigned pk2(float a, float b) {
  return (unsigned)(unsigned short)f2bf(a) | ((unsigned)(unsigned short)f2bf(b) << 16);
}

static __device__ __forceinline__ int wave_incl_scan(int x) {
  int lane = threadIdx.x & 63;
  #pragma unroll
  for (int off = 1; off < 64; off <<= 1) {
    int y = __shfl_up(x, off, 64);
    if (lane >= off) x += y;
  }
  return x;
}

// global->LDS direct stage: no VGPR destination => no register-pressure war.
// dest = uniform lds base + lane*4; source = per-lane global address.
#define GLOAD_LDS4(g, l) __builtin_amdgcn_global_load_lds(                     \
    (const __attribute__((address_space(1))) void*)(g),                        \
    (__attribute__((address_space(3))) void*)(l), 4, 0, 0)
#define SB() __builtin_amdgcn_sched_barrier(0)
#define WAIT_VM(N) do { asm volatile("s_waitcnt vmcnt(" #N ")" ::: "memory"); SB(); } while (0)
// raw barrier: does NOT drain vmcnt (round-8 lesson); LDS visibility via lgkmcnt.
#define BAR_LDS() do { asm volatile("s_waitcnt lgkmcnt(0)" ::: "memory"); \
                       __builtin_amdgcn_s_barrier(); SB(); } while (0)

// ---------- fused prep: edge hist | h0 gather | weight tiles ----------
__global__ void k_prep(const int* __restrict__ ei, const int* __restrict__ et,
                       int* __restrict__ hist,
                       const int* __restrict__ nid, const float* __restrict__ emb,
                       unsigned* __restrict__ h,
                       const float* __restrict__ wrel, const float* __restrict__ wself,
                       short* __restrict__ wt) {
  int b = blockIdx.x, t = threadIdx.x;
  if (b < EB) {
    int e = b * 256 + t;
    if (e < E_EDGES) {
      int key = et[e] * N_NODES + ei[E_EDGES + e];
      atomicAdd(&hist[key], 1);
    }
  } else if (b < EB + H0B) {
    int g = (b - EB) * 256 + t;                    // over N*32
    int n = g >> 5, q = g & 31;
    float4 v = *(const float4*)(emb + (size_t)nid[n] * DIM + q * 4);
    uint2 pk;
    pk.x = pk2(v.x, v.y);
    pk.y = pk2(v.z, v.w);
    *(uint2*)(h + (size_t)n * 64 + q * 2) = pk;
  } else {
    // wt layout: [l][g=k/32][nt8=n/16] tile [16 rA][32 q] shorts (1KB)
    int idx = (b - EB - H0B) * 256 + t;
    int within = idx & 511;
    int tile = idx >> 9;
    int rA = within >> 5, q = within & 31;
    int nt8 = tile & 7;
    int lg = tile >> 3;
    int l = lg / NG, g = lg % NG;
    int n = nt8 * 16 + rA;
    int k = g * 32 + q;
    float v;
    if (k < N_REL * DIM) {
      int r = k >> 7, d = k & 127;
      v = wrel[(((size_t)l * N_REL + r) * DIM + d) * DIM + n];
    } else {
      int d = k - N_REL * DIM;
      v = wself[((size_t)l * DIM + d) * DIM + n];
    }
    wt[idx] = f2bf(v);
  }
}

__global__ void k_bsum(const int* __restrict__ hist, int* __restrict__ bsum) {
  int t = threadIdx.x;
  int v = hist[blockIdx.x * 256 + t];
  #pragma unroll
  for (int off = 32; off; off >>= 1) v += __shfl_xor(v, off, 64);
  __shared__ int s4[4];
  if ((t & 63) == 0) s4[t >> 6] = v;
  __syncthreads();
  if (t == 0) bsum[blockIdx.x] = s4[0] + s4[1] + s4[2] + s4[3];
}

__global__ void k_bscan(int* __restrict__ bsum) {   // 1 block, 1024 threads
  int t = threadIdx.x;
  int v[4], loc[4], s = 0;
  #pragma unroll
  for (int i = 0; i < 4; i++) {
    int idx = t * 4 + i;
    v[i] = (idx < NBLK_SEG) ? bsum[idx] : 0;
    loc[i] = s; s += v[i];
  }
  int incl = wave_incl_scan(s);
  __shared__ int wsum[16];
  int wid = t >> 6, lane = t & 63;
  if (lane == 63) wsum[wid] = incl;
  __syncthreads();
  if (t < 16) {
    int x = wsum[t];
    #pragma unroll
    for (int off = 1; off < 16; off <<= 1) {
      int y = __shfl_up(x, off, 64);
      if (t >= off) x += y;
    }
    wsum[t] = x;
  }
  __syncthreads();
  int wexcl = wid ? wsum[wid - 1] : 0;
  int texcl = wexcl + incl - s;
  #pragma unroll
  for (int i = 0; i < 4; i++) {
    int idx = t * 4 + i;
    if (idx < NBLK_SEG) bsum[idx] = texcl + loc[i];
  }
}

__global__ void k_offsets(const int* __restrict__ hist, const int* __restrict__ bsum,
                          int* __restrict__ offs, int* __restrict__ cursor) {
  int t = threadIdx.x;
  int g = blockIdx.x * 256 + t;
  int v = hist[g];
  int incl = wave_incl_scan(v);
  __shared__ int wsum[4];
  int wid = t >> 6, lane = t & 63;
  if (lane == 63) wsum[wid] = incl;
  __syncthreads();
  int wexcl = 0;
  for (int i = 0; i < wid; i++) wexcl += wsum[i];
  int off = bsum[blockIdx.x] + wexcl + incl - v;
  offs[g] = off;
  cursor[g] = off;
  if (g == NK - 1) offs[NK] = off + v;
}

__global__ void k_scatter(const int* __restrict__ ei, const int* __restrict__ et,
                          int* __restrict__ cursor, int* __restrict__ ssrc) {
  int e = blockIdx.x * 256 + threadIdx.x;
  if (e >= E_EDGES) return;
  int src = ei[e];
  int key = et[e] * N_NODES + ei[E_EDGES + e];
  int pos = atomicAdd(&cursor[key], 1);
  ssrc[pos] = src;
}

// ---------- fused layer: unified waves, LDS-staged edge pipeline ----------
// 8 waves x 8 dst rows. Per relation p: J(p)=1 gload_lds of 64 edge ids,
// S(p)=13 gload_lds of edge h-rows (256B each). Steady phase:
//   WAIT(13) [J(p+1) in]; issue J(p+2); issue S(p+1); WAIT(14) [S(p) in];
//   accum(p) from LDS -> As; s_barrier(no drain); MFMA(p); s_barrier.
__global__ __launch_bounds__(512, 4)
void k_layer(const unsigned* __restrict__ hin, const int* __restrict__ offs,
             const int* __restrict__ ssrc, const short* __restrict__ wt,
             unsigned* __restrict__ hout) {
  __shared__ unsigned As[BM][68];              // 17.4 KB (272B rows, 16B-aligned)
  __shared__ unsigned ebuf[8][2][EMAX][64];    // 53.2 KB staged edge rows
  __shared__ int jbuf[8][2][64];               // 4 KB staged edge ids
  __shared__ int offsS[16][66];                // 4.2 KB segment boundaries
  int t = threadIdx.x;
  int w = t >> 6, lane = t & 63;
  int quad = lane >> 4, rA = lane & 15;
  int w8 = w * 8;
  int wm16 = (w >> 1) * 16, wn4 = (w & 1) * 4;
  int row0 = blockIdx.x * BM;

  for (int idx = t; idx < 16 * 80; idx += 512) {
    int it = idx / 80, rr = idx - it * 80;
    if (rr < 65) offsS[it][rr] = offs[min(it * N_NODES + row0 + rr, NK)];
  }
  BAR_LDS();

  floatx4 acc[4];
  #pragma unroll
  for (int nt = 0; nt < 4; ++nt) acc[nt] = (floatx4)0.f;

  auto issue_j = [&](int p, int jb) {
    int o0 = offsS[min(p, 15)][w8];
    GLOAD_LDS4(ssrc + min(o0 + lane, E_EDGES - 1), &jbuf[w][jb][0]);
  };
  auto issue_s = [&](int p) {
    int bix = p & 1;
    #pragma unroll
    for (int e = 0; e < EMAX; ++e) {
      int sid = jbuf[w][bix][e];               // uniform LDS read (broadcast)
      GLOAD_LDS4(hin + (size_t)sid * 64 + lane, &ebuf[w][bix][e][0]);
    }
  };
  auto accum_f = [&](int p) {
    int bix = p & 1;
    int olv = offsS[p][w8 + min(lane, 8)];     // lanes 0..8 meaningful
    int o0 = __builtin_amdgcn_readfirstlane(olv);
    int total = __builtin_amdgcn_readlane(olv, 8) - o0;
    int nxt = __shfl(olv, lane + 1, 64);
    int cnl = nxt - olv;
    float ivf = 1.0f / (float)(cnl > 0 ? cnl : 1);   // one rcp, lane-parallel
    int ivb = __builtin_bit_cast(int, ivf);
    int k = 0;
    int nb = __builtin_amdgcn_readlane(olv, 1) - o0;
    float r0 = 0.f, r1 = 0.f;
    auto close1 = [&]() {
      float f = __builtin_bit_cast(float, __builtin_amdgcn_readlane(ivb, k));
      float a = r0 * f, b = r1 * f;
      unsigned pk;
      asm("v_cvt_pk_bf16_f32 %0, %1, %2" : "=v"(pk) : "v"(a), "v"(b));  // RNE
      As[w8 + k][lane] = pk;
      r0 = 0.f; r1 = 0.f;
      ++k;
      nb = __builtin_amdgcn_readlane(olv, min(k + 1, 8)) - o0;
    };
    #pragma unroll
    for (int e = 0; e < EMAX; ++e) {
      while (k < 8 && nb == e) close1();       // close segs ending here (incl empties)
      if (e < total) {                         // wave-uniform branch
        unsigned uv = ebuf[w][bix][e][lane];
        r0 += bf_lo(uv); r1 += bf_hi(uv);
      }
    }
    if (total > EMAX) {                        // rare (~0.3%) serial tail; drains pipe, self-heals
      for (int e = EMAX; e < total; ++e) {
        while (k < 8 && nb == e) close1();
        int sr = __builtin_amdgcn_readfirstlane(ssrc[o0 + e]);
        unsigned uu = hin[(size_t)sr * 64 + lane];
        r0 += bf_lo(uu); r1 += bf_hi(uu);
      }
    }
    while (k < 8) close1();
  };
  auto do_mfma = [&](int p) {
    const short* arow = (const short*)&As[wm16 + rA][0];
    #pragma unroll
    for (int ks = 0; ks < 4; ++ks) {
      short8 a0 = *(const short8*)(arow + ks * 32 + quad * 8);
      int kg = p * 4 + ks;
      const short* bp = wt + (size_t)(kg * 8 + wn4) * 512 + rA * 32 + quad * 8;
      #pragma unroll
      for (int nt = 0; nt < 4; ++nt) {
        short8 b = *(const short8*)(bp + nt * 512);   // 1KB tile, L2-hot
        acc[nt] = __builtin_amdgcn_mfma_f32_16x16x32_bf16(a0, b, acc[nt], 0, 0, 0);
      }
    }
  };

  // ---- prologue ----
  issue_j(0, 0);                // [1]
  WAIT_VM(0);
  issue_j(1, 1);                // [1]
  SB();
  issue_s(0);                   // [14]
  SB();
  WAIT_VM(13);                  // J(1) done
  issue_j(2, 0);                // [14]
  SB();
  issue_s(1);                   // [27]
  SB();
  WAIT_VM(14);                  // S(0) done
  accum_f(0);
  BAR_LDS();
  do_mfma(0);
  BAR_LDS();

  // ---- main loop: relations 1..15 ----
  for (int p = 1; p <= 15; ++p) {
    WAIT_VM(13);                // J(p+1) done
    issue_j(p + 2, p & 1);      // (p+2)&1 == p&1; p+2>15 clamped dummy
    SB();
    issue_s(p + 1);             // dummy at p=15 (valid rows, never read)
    SB();
    WAIT_VM(14);                // S(p) done
    accum_f(p);
    BAR_LDS();
    do_mfma(p);
    BAR_LDS();
  }

  // ---- self slot (compiler loads; one-time drain is fine) ----
  #pragma unroll
  for (int j = 0; j < 8; ++j) {
    int lr = min(row0 + w8 + j, N_NODES - 1);
    As[w8 + j][lane] = hin[(size_t)lr * 64 + lane];
  }
  BAR_LDS();
  do_mfma(16);

  // epilogue: C row=quad*4+j, col=rA within each 16x16 tile
  #pragma unroll
  for (int nt = 0; nt < 4; ++nt)
    #pragma unroll
    for (int j = 0; j < 4; ++j) {
      int row = row0 + wm16 + quad * 4 + j;
      int col = (w & 1) * 64 + nt * 16 + rA;
      if (row < N_NODES)
        ((short*)hout)[(size_t)row * DIM + col] = f2bf(fmaxf(acc[nt][j], 0.f));
    }
}

// ---------- scoring (bf16 h) ----------
__global__ void k_score(const unsigned* __restrict__ h, const int* __restrict__ heads,
                        const int* __restrict__ rels, const int* __restrict__ tails,
                        const float* __restrict__ rel_emb, const float* __restrict__ path_feat,
                        const int* __restrict__ task_idx, const float* __restrict__ delta_w,
                        const float* __restrict__ lambda_logit, const float* __restrict__ rule_init,
                        float* __restrict__ out) {
  int q = (blockIdx.x * 256 + threadIdx.x) >> 6;
  int lane = threadIdx.x & 63;
  int hd = heads[q], tl = tails[q], rl = rels[q];
  unsigned ua = h[(size_t)hd * 64 + lane];
  unsigned uc = h[(size_t)tl * 64 + lane];
  float2 r = *(const float2*)(rel_emb + (size_t)rl * DIM + lane * 2);
  float s = bf_lo(ua) * r.x * bf_lo(uc) + bf_hi(ua) * r.y * bf_hi(uc);
  #pragma unroll
  for (int off = 32; off; off >>= 1) s += __shfl_xor(s, off, 64);
  if (lane == 0) {
    int task = task_idx[0];
    float sp = 0.f;
    #pragma unroll
    for (int p = 0; p < PATH_DIM; p++)
      sp += path_feat[q * PATH_DIM + p] *
            (rule_init[task * PATH_DIM + p] + delta_w[task * PATH_DIM + p]);
    float lam = 1.f / (1.f + __expf(-lambda_logit[task]));
    out[q] = lam * s + (1.f - lam) * sp;
  }
}

extern "C" void kernel_launch(void* const* d_in, const int* in_sizes, int n_in,
                              void* d_out, int out_size, void* d_ws, size_t ws_size,
                              hipStream_t stream) {
  const int*   node_ids   = (const int*)d_in[0];
  const int*   edge_index = (const int*)d_in[1];
  const int*   edge_type  = (const int*)d_in[2];
  const int*   heads      = (const int*)d_in[3];
  const int*   rels       = (const int*)d_in[4];
  const int*   tails      = (const int*)d_in[5];
  const float* path_feat  = (const float*)d_in[6];
  const int*   task_idx   = (const int*)d_in[7];
  const float* entity_emb = (const float*)d_in[8];
  const float* rel_emb    = (const float*)d_in[9];
  const float* W_self     = (const float*)d_in[10];
  const float* W_rel      = (const float*)d_in[11];
  const float* delta_w    = (const float*)d_in[12];
  const float* lambda_lg  = (const float*)d_in[13];
  const float* rule_init  = (const float*)d_in[14];

  char* ws = (char*)d_ws;
  size_t off = 0;
  auto alloc = [&](size_t bytes) -> void* {
    void* p = ws + off;
    off = (off + bytes + 255) & ~(size_t)255;
    return p;
  };
  unsigned* h_a    = (unsigned*)alloc((size_t)N_NODES * DIM * 2);
  unsigned* h_b    = (unsigned*)alloc((size_t)N_NODES * DIM * 2);
  short*    wt     = (short*)alloc((size_t)2 * NG * 8 * 512 * 2);
  int*      offs   = (int*)alloc((size_t)(NK + 1) * 4);
  int*      ssrc   = (int*)alloc((size_t)E_EDGES * 4);
  int*      hist   = (int*)alloc((size_t)(NK + 1) * 4);
  int*      cursor = (int*)alloc((size_t)NK * 4);
  int*      bsum   = (int*)alloc((size_t)NBLK_SEG * 4);

  hipMemsetAsync(hist, 0, (size_t)(NK + 1) * 4, stream);
  k_prep<<<EB + H0B + WCB, 256, 0, stream>>>(edge_index, edge_type, hist,
                                             node_ids, entity_emb, h_a,
                                             W_rel, W_self, wt);
  k_bsum<<<NBLK_SEG, 256, 0, stream>>>(hist, bsum);
  k_bscan<<<1, 1024, 0, stream>>>(bsum);
  k_offsets<<<NBLK_SEG, 256, 0, stream>>>(hist, bsum, offs, cursor);
  k_scatter<<<EB, 256, 0, stream>>>(edge_index, edge_type, cursor, ssrc);

  const unsigned* hin = h_a;
  unsigned* hout = h_b;
  int nblk = (N_NODES + BM - 1) / BM;
  for (int l = 0; l < 2; l++) {
    k_layer<<<nblk, 512, 0, stream>>>(hin, offs, ssrc,
                                      wt + (size_t)l * NG * 8 * 512, hout);
    const unsigned* tmp = hout;
    hout = (unsigned*)hin;
    hin = tmp;
  }
  k_score<<<NQ / 4, 256, 0, stream>>>(hin, heads, rels, tails, rel_emb, path_feat,
                                      task_idx, delta_w, lambda_lg, rule_init,
                                      (float*)d_out);
}

// Round 11
// 510.939 us; speedup vs baseline: 1.0986x; 1.0986x over previous
//
#include <hip/hip_runtime.h>

#define N_NODES 50000
#define N_ENT   100000
#define N_REL   16
#define DIM     128
#define E_EDGES 600000
#define NQ      8192
#define PATH_DIM 5
#define NK      (N_NODES * N_REL)        /* 800000 (rel,dst) segments, rel-major */
#define NBLK_SEG (NK / 256)              /* 3125 */
#define KTOT    (N_REL * DIM + DIM)      /* 2176 */
#define NG      (KTOT / 32)              /* 68 */
#define BM      64                       /* rows per block (4 waves x 16) */
#define EB      ((E_EDGES + 255) / 256)
#define H0B     ((N_NODES * 32) / 256)
#define WCB     ((2 * NG * 8 * 512) / 256)

typedef __attribute__((ext_vector_type(8))) short short8;
typedef __attribute__((ext_vector_type(4))) float floatx4;
typedef __attribute__((ext_vector_type(4))) unsigned uintx4;

static __device__ __forceinline__ short f2bf(float x) {
  unsigned u = __builtin_bit_cast(unsigned, x);
  u = (u + 0x7FFFu + ((u >> 16) & 1u)) >> 16;   // RNE
  return (short)u;
}
static __device__ __forceinline__ float bf_lo(unsigned u) {
  return __builtin_bit_cast(float, u << 16);
}
static __device__ __forceinline__ float bf_hi(unsigned u) {
  return __builtin_bit_cast(float, u & 0xffff0000u);
}
static __device__ __forceinline__ unsigned pk2(float a, float b) {
  return (unsigned)(unsigned short)f2bf(a) | ((unsigned)(unsigned short)f2bf(b) << 16);
}

static __device__ __forceinline__ int wave_incl_scan(int x) {
  int lane = threadIdx.x & 63;
  #pragma unroll
  for (int off = 1; off < 64; off <<= 1) {
    int y = __shfl_up(x, off, 64);
    if (lane >= off) x += y;
  }
  return x;
}

// ---------- fused prep: edge hist | h0 gather | weight tiles ----------
__global__ void k_prep(const int* __restrict__ ei, const int* __restrict__ et,
                       int* __restrict__ hist,
                       const int* __restrict__ nid, const float* __restrict__ emb,
                       unsigned* __restrict__ h,
                       const float* __restrict__ wrel, const float* __restrict__ wself,
                       short* __restrict__ wt) {
  int b = blockIdx.x, t = threadIdx.x;
  if (b < EB) {
    int e = b * 256 + t;
    if (e < E_EDGES) {
      int key = et[e] * N_NODES + ei[E_EDGES + e];
      atomicAdd(&hist[key], 1);
    }
  } else if (b < EB + H0B) {
    int g = (b - EB) * 256 + t;                    // over N*32
    int n = g >> 5, q = g & 31;
    float4 v = *(const float4*)(emb + (size_t)nid[n] * DIM + q * 4);
    uint2 pk;
    pk.x = pk2(v.x, v.y);
    pk.y = pk2(v.z, v.w);
    *(uint2*)(h + (size_t)n * 64 + q * 2) = pk;
  } else {
    // wt layout: [l][g=k/32][nt8=n/16] tile [16 rA][32 q] shorts (1KB)
    int idx = (b - EB - H0B) * 256 + t;
    int within = idx & 511;
    int tile = idx >> 9;
    int rA = within >> 5, q = within & 31;
    int nt8 = tile & 7;
    int lg = tile >> 3;
    int l = lg / NG, g = lg % NG;
    int n = nt8 * 16 + rA;
    int k = g * 32 + q;
    float v;
    if (k < N_REL * DIM) {
      int r = k >> 7, d = k & 127;
      v = wrel[(((size_t)l * N_REL + r) * DIM + d) * DIM + n];
    } else {
      int d = k - N_REL * DIM;
      v = wself[((size_t)l * DIM + d) * DIM + n];
    }
    wt[idx] = f2bf(v);
  }
}

__global__ void k_bsum(const int* __restrict__ hist, int* __restrict__ bsum) {
  int t = threadIdx.x;
  int v = hist[blockIdx.x * 256 + t];
  #pragma unroll
  for (int off = 32; off; off >>= 1) v += __shfl_xor(v, off, 64);
  __shared__ int s4[4];
  if ((t & 63) == 0) s4[t >> 6] = v;
  __syncthreads();
  if (t == 0) bsum[blockIdx.x] = s4[0] + s4[1] + s4[2] + s4[3];
}

__global__ void k_bscan(int* __restrict__ bsum) {   // 1 block, 1024 threads
  int t = threadIdx.x;
  int v[4], loc[4], s = 0;
  #pragma unroll
  for (int i = 0; i < 4; i++) {
    int idx = t * 4 + i;
    v[i] = (idx < NBLK_SEG) ? bsum[idx] : 0;
    loc[i] = s; s += v[i];
  }
  int incl = wave_incl_scan(s);
  __shared__ int wsum[16];
  int wid = t >> 6, lane = t & 63;
  if (lane == 63) wsum[wid] = incl;
  __syncthreads();
  if (t < 16) {
    int x = wsum[t];
    #pragma unroll
    for (int off = 1; off < 16; off <<= 1) {
      int y = __shfl_up(x, off, 64);
      if (t >= off) x += y;
    }
    wsum[t] = x;
  }
  __syncthreads();
  int wexcl = wid ? wsum[wid - 1] : 0;
  int texcl = wexcl + incl - s;
  #pragma unroll
  for (int i = 0; i < 4; i++) {
    int idx = t * 4 + i;
    if (idx < NBLK_SEG) bsum[idx] = texcl + loc[i];
  }
}

__global__ void k_offsets(const int* __restrict__ hist, const int* __restrict__ bsum,
                          int* __restrict__ offs, int* __restrict__ cursor) {
  int t = threadIdx.x;
  int g = blockIdx.x * 256 + t;
  int v = hist[g];
  int incl = wave_incl_scan(v);
  __shared__ int wsum[4];
  int wid = t >> 6, lane = t & 63;
  if (lane == 63) wsum[wid] = incl;
  __syncthreads();
  int wexcl = 0;
  for (int i = 0; i < wid; i++) wexcl += wsum[i];
  int off = bsum[blockIdx.x] + wexcl + incl - v;
  offs[g] = off;
  cursor[g] = off;
  if (g == NK - 1) offs[NK] = off + v;
}

__global__ void k_scatter(const int* __restrict__ ei, const int* __restrict__ et,
                          int* __restrict__ cursor, int* __restrict__ ssrc) {
  int e = blockIdx.x * 256 + threadIdx.x;
  if (e >= E_EDGES) return;
  int src = ei[e];
  int key = et[e] * N_NODES + ei[E_EDGES + e];
  int pos = atomicAdd(&cursor[key], 1);
  ssrc[pos] = src;
}

// ---------- fused layer: barrier-free, per-lane segments, A in registers ----------
// Wave owns 16 rows. MFMA A-layout lane=(row rA, chans quad*8+ks*32..+7) means
// each lane computes ITS OWN segment mean for ITS OWN channel slices with plain
// per-lane predicated loads: no readlane fan-out, no LDS A-tile, no K-loop
// barriers. 4 quads of a segment together read the full 256B row (coalesced).
__global__ __launch_bounds__(256, 3)
void k_layer(const unsigned* __restrict__ hin, const int* __restrict__ offs,
             const int* __restrict__ ssrc, const short* __restrict__ wt,
             unsigned* __restrict__ hout) {
  __shared__ int offsS[16][66];       // per-rel segment boundaries for block rows
  int t = threadIdx.x;
  int w = t >> 6, lane = t & 63;
  int quad = lane >> 4, rA = lane & 15;
  int w16 = w * 16;
  int row0 = blockIdx.x * BM;

  for (int idx = t; idx < 16 * 80; idx += 256) {
    int r = idx / 80, j = idx - r * 80;
    if (j < 65) offsS[r][j] = offs[min(r * N_NODES + row0 + j, NK)];
  }
  __syncthreads();                    // the only block barrier

  floatx4 acc[8];
  #pragma unroll
  for (int nt = 0; nt < 8; ++nt) acc[nt] = (floatx4)0.f;

  const short* hb = (const short*)hin;

  for (int r = 0; r < 17; ++r) {
    short8 af[4];
    if (r < 16) {
      int o = offsS[r][w16 + rA];
      int c = offsS[r][w16 + rA + 1] - o;     // lane-local count
      int mc = c;
      #pragma unroll
      for (int sh = 32; sh; sh >>= 1) mc = max(mc, __shfl_xor(mc, sh, 64));
      float s[4][8];
      #pragma unroll
      for (int ks = 0; ks < 4; ++ks)
        #pragma unroll
        for (int m = 0; m < 8; ++m) s[ks][m] = 0.f;
      int eid = (c > 0) ? ssrc[o] : 0;        // 4 quad-lanes share addr (broadcast)
      for (int i = 0; i < mc; ++i) {          // wave-uniform trip count
        int eidn = (i + 1 < c) ? ssrc[o + i + 1] : 0;   // prefetch next id
        if (i < c) {
          const short* hp = hb + (size_t)eid * DIM + quad * 8;
          #pragma unroll
          for (int ks = 0; ks < 4; ++ks) {    // 4 x 16B; quads cover 256B row
            uint4 d = *(const uint4*)(hp + ks * 32);
            s[ks][0] += bf_lo(d.x); s[ks][1] += bf_hi(d.x);
            s[ks][2] += bf_lo(d.y); s[ks][3] += bf_hi(d.y);
            s[ks][4] += bf_lo(d.z); s[ks][5] += bf_hi(d.z);
            s[ks][6] += bf_lo(d.w); s[ks][7] += bf_hi(d.w);
          }
        }
        eid = eidn;
      }
      float inv = 1.0f / (float)(c > 0 ? c : 1);  // lane-local, no readlane
      #pragma unroll
      for (int ks = 0; ks < 4; ++ks) {
        uintx4 ap;
        #pragma unroll
        for (int m = 0; m < 4; ++m) {
          float a = s[ks][2 * m] * inv, b = s[ks][2 * m + 1] * inv;
          unsigned pk;
          asm("v_cvt_pk_bf16_f32 %0, %1, %2" : "=v"(pk) : "v"(a), "v"(b));  // RNE
          ap[m] = pk;
        }
        af[ks] = __builtin_bit_cast(short8, ap);
      }
    } else {
      // self slot: A-frag = raw bf16 slices of own h row
      int lr = min(row0 + w16 + rA, N_NODES - 1);
      const short* hp = hb + (size_t)lr * DIM + quad * 8;
      #pragma unroll
      for (int ks = 0; ks < 4; ++ks) af[ks] = *(const short8*)(hp + ks * 32);
    }
    #pragma unroll
    for (int ks = 0; ks < 4; ++ks) {
      const short* bp = wt + (size_t)((r * 4 + ks) * 8) * 512 + rA * 32 + quad * 8;
      #pragma unroll
      for (int nt = 0; nt < 8; ++nt) {
        short8 b = *(const short8*)(bp + nt * 512);   // 1KB tile, L2-hot
        acc[nt] = __builtin_amdgcn_mfma_f32_16x16x32_bf16(af[ks], b, acc[nt], 0, 0, 0);
      }
    }
  }
  // epilogue: C row=quad*4+j, col=nt*16+rA
  #pragma unroll
  for (int nt = 0; nt < 8; ++nt)
    #pragma unroll
    for (int j = 0; j < 4; ++j) {
      int row = row0 + w16 + quad * 4 + j;
      int col = nt * 16 + rA;
      if (row < N_NODES)
        ((short*)hout)[(size_t)row * DIM + col] = f2bf(fmaxf(acc[nt][j], 0.f));
    }
}

// ---------- scoring (bf16 h) ----------
__global__ void k_score(const unsigned* __restrict__ h, const int* __restrict__ heads,
                        const int* __restrict__ rels, const int* __restrict__ tails,
                        const float* __restrict__ rel_emb, const float* __restrict__ path_feat,
                        const int* __restrict__ task_idx, const float* __restrict__ delta_w,
                        const float* __restrict__ lambda_logit, const float* __restrict__ rule_init,
                        float* __restrict__ out) {
  int q = (blockIdx.x * 256 + threadIdx.x) >> 6;
  int lane = threadIdx.x & 63;
  int hd = heads[q], tl = tails[q], rl = rels[q];
  unsigned ua = h[(size_t)hd * 64 + lane];
  unsigned uc = h[(size_t)tl * 64 + lane];
  float2 r = *(const float2*)(rel_emb + (size_t)rl * DIM + lane * 2);
  float s = bf_lo(ua) * r.x * bf_lo(uc) + bf_hi(ua) * r.y * bf_hi(uc);
  #pragma unroll
  for (int off = 32; off; off >>= 1) s += __shfl_xor(s, off, 64);
  if (lane == 0) {
    int task = task_idx[0];
    float sp = 0.f;
    #pragma unroll
    for (int p = 0; p < PATH_DIM; p++)
      sp += path_feat[q * PATH_DIM + p] *
            (rule_init[task * PATH_DIM + p] + delta_w[task * PATH_DIM + p]);
    float lam = 1.f / (1.f + __expf(-lambda_logit[task]));
    out[q] = lam * s + (1.f - lam) * sp;
  }
}

extern "C" void kernel_launch(void* const* d_in, const int* in_sizes, int n_in,
                              void* d_out, int out_size, void* d_ws, size_t ws_size,
                              hipStream_t stream) {
  const int*   node_ids   = (const int*)d_in[0];
  const int*   edge_index = (const int*)d_in[1];
  const int*   edge_type  = (const int*)d_in[2];
  const int*   heads      = (const int*)d_in[3];
  const int*   rels       = (const int*)d_in[4];
  const int*   tails      = (const int*)d_in[5];
  const float* path_feat  = (const float*)d_in[6];
  const int*   task_idx   = (const int*)d_in[7];
  const float* entity_emb = (const float*)d_in[8];
  const float* rel_emb    = (const float*)d_in[9];
  const float* W_self     = (const float*)d_in[10];
  const float* W_rel      = (const float*)d_in[11];
  const float* delta_w    = (const float*)d_in[12];
  const float* lambda_lg  = (const float*)d_in[13];
  const float* rule_init  = (const float*)d_in[14];

  char* ws = (char*)d_ws;
  size_t off = 0;
  auto alloc = [&](size_t bytes) -> void* {
    void* p = ws + off;
    off = (off + bytes + 255) & ~(size_t)255;
    return p;
  };
  unsigned* h_a    = (unsigned*)alloc((size_t)N_NODES * DIM * 2);
  unsigned* h_b    = (unsigned*)alloc((size_t)N_NODES * DIM * 2);
  short*    wt     = (short*)alloc((size_t)2 * NG * 8 * 512 * 2);
  int*      offs   = (int*)alloc((size_t)(NK + 1) * 4);
  int*      ssrc   = (int*)alloc((size_t)E_EDGES * 4);
  int*      hist   = (int*)alloc((size_t)(NK + 1) * 4);
  int*      cursor = (int*)alloc((size_t)NK * 4);
  int*      bsum   = (int*)alloc((size_t)NBLK_SEG * 4);

  hipMemsetAsync(hist, 0, (size_t)(NK + 1) * 4, stream);
  k_prep<<<EB + H0B + WCB, 256, 0, stream>>>(edge_index, edge_type, hist,
                                             node_ids, entity_emb, h_a,
                                             W_rel, W_self, wt);
  k_bsum<<<NBLK_SEG, 256, 0, stream>>>(hist, bsum);
  k_bscan<<<1, 1024, 0, stream>>>(bsum);
  k_offsets<<<NBLK_SEG, 256, 0, stream>>>(hist, bsum, offs, cursor);
  k_scatter<<<EB, 256, 0, stream>>>(edge_index, edge_type, cursor, ssrc);

  const unsigned* hin = h_a;
  unsigned* hout = h_b;
  int nblk = (N_NODES + BM - 1) / BM;
  for (int l = 0; l < 2; l++) {
    k_layer<<<nblk, 256, 0, stream>>>(hin, offs, ssrc,
                                      wt + (size_t)l * NG * 8 * 512, hout);
    const unsigned* tmp = hout;
    hout = (unsigned*)hin;
    hin = tmp;
  }
  k_score<<<NQ / 4, 256, 0, stream>>>(hin, heads, rels, tails, rel_emb, path_feat,
                                      task_idx, delta_w, lambda_lg, rule_init,
                                      (float*)d_out);
}